// Round 11
// baseline (241.561 us; speedup 1.0000x reference)
//
#include <hip/hip_runtime.h>

constexpr int Bz = 2, Lz = 2048, Dz = 1024, Hz = 16, HDz = 64;
constexpr int QSZ = Bz * Hz * Lz * HDz;  // 4,194,304 elements per tensor
constexpr int SPLIT = 2;                 // key-range split for attention
constexpr int KSPAN = Lz / SPLIT;        // 1024 keys per split

typedef __attribute__((ext_vector_type(8))) __bf16 bf16x8;
typedef __attribute__((ext_vector_type(2))) __bf16 bf16x2;
typedef __attribute__((ext_vector_type(4))) float f32x4;

__device__ __forceinline__ float b2f(unsigned int u) {
    union { float f; unsigned int i; } c; c.i = u << 16; return c.f;
}
__device__ __forceinline__ unsigned short f2b(float x) {
    union { float f; unsigned int u; } c; c.f = x;
    unsigned int u = c.u;
    return (unsigned short)((u + 0x7fffu + ((u >> 16) & 1u)) >> 16);
}
// HW packed RNE f32->bf16 pair (v_cvt_pk_bf16_f32 on gfx950; fptrunc is RNE)
__device__ __forceinline__ unsigned int pkbf(float a, float b) {
    union { bf16x2 v; unsigned int u; } c;
    c.v = (bf16x2){(__bf16)a, (__bf16)b};
    return c.u;
}
__device__ __forceinline__ void ld8(const float* p, float* f) {
    float4 a = *(const float4*)p, b = *(const float4*)(p + 4);
    f[0] = a.x; f[1] = a.y; f[2] = a.z; f[3] = a.w;
    f[4] = b.x; f[5] = b.y; f[6] = b.z; f[7] = b.w;
}
// ushort index into a [rows][64]-bf16 LDS tile, 16B-chunk XOR swizzle
__device__ __forceinline__ int swb(int row, int e) {
    return row * 64 + ((((e >> 3) ^ row) & 7) << 3) + (e & 7);
}

__global__ void ws_sentinel(float* __restrict__ out) {
    if (threadIdx.x == 0 && blockIdx.x == 0) out[0] = 100.0f;
}

// ---------------- prep: cvt_x + cvt_w + lsb-zero fused (one dispatch) ------------
// cvt_x: Bz*Lz*Dz = 4,194,304 elems / (256 thr * 8) = 2048 blocks  [r10 bug: 4096]
__global__ __launch_bounds__(256) void prep(
    const float* __restrict__ x,
    const float* __restrict__ Wq, const float* __restrict__ Wk,
    const float* __restrict__ Wv, const float* __restrict__ Wo,
    unsigned short* __restrict__ xb, unsigned short* __restrict__ Wt,
    unsigned short* __restrict__ Wot, float* __restrict__ lsb) {
    const int bid = blockIdx.x, tid = threadIdx.x;
    if (bid < 2048) {                      // cvt_x
        int idx = (bid * 256 + tid) * 8;
        float f[8]; ld8(x + idx, f);
        unsigned int o[4];
        #pragma unroll
        for (int j = 0; j < 4; ++j) o[j] = pkbf(f[2 * j], f[2 * j + 1]);
        *(uint4*)(xb + idx) = *(uint4*)o;
    } else if (bid < 2048 + 1024) {        // cvt_w (transpose to n-major)
        int zz = bid - 2048;
        int z = zz >> 8, y = (zz >> 4) & 15, xk = zz & 15;
        int kseg = xk * 4 + (tid >> 6);
        int k0 = kseg * 16;
        unsigned short o[16];
        if (z < 3) {
            const float* W = (z == 0) ? Wq : (z == 1) ? Wk : Wv;
            const int h = y, n = tid & 63;
            const float* src = W + (size_t)h * Dz * HDz;
            #pragma unroll
            for (int j = 0; j < 16; ++j) o[j] = f2b(src[(size_t)(k0 + j) * HDz + n]);
            unsigned short* dst = Wt + ((size_t)((z * Hz + h) * HDz) + n) * Dz + k0;
            *(uint4*)dst = *(uint4*)o;
            *(uint4*)(dst + 8) = *(uint4*)(o + 8);
        } else {
            const int n = y * 64 + (tid & 63);
            #pragma unroll
            for (int j = 0; j < 16; ++j) o[j] = f2b(Wo[(size_t)(k0 + j) * Dz + n]);
            unsigned short* dst = Wot + (size_t)n * Dz + k0;
            *(uint4*)dst = *(uint4*)o;
            *(uint4*)(dst + 8) = *(uint4*)(o + 8);
        }
    } else {                               // zero lsb (B*H*L = 65536 floats)
        int i = (bid - 3072) * 1024 + tid * 4;
        *(float4*)(lsb + i) = (float4){0.f, 0.f, 0.f, 0.f};
    }
}

// ---------------- QKV projection v2: unified GEMM (4096x1024)x(1024x3072) --------
// 128x128 tile, BK=64; B = Wt rows n in [0,3072) with n -> (which,h,e) scatter.
__global__ __launch_bounds__(256) void qkv_mfma(
    const unsigned short* __restrict__ xb, const unsigned short* __restrict__ Wt,
    const float* __restrict__ bq, const float* __restrict__ bk,
    const float* __restrict__ bv, unsigned short* __restrict__ qkv) {
    const int rblk = blockIdx.x;   // 0..31
    const int nblk = blockIdx.y;   // 0..23
    const int tid = threadIdx.x, wave = tid >> 6, lane = tid & 63;
    const int quad = lane >> 4, l16 = lane & 15;
    const int wm = wave >> 1, wn = wave & 1;

    __shared__ __align__(16) unsigned short As[128 * 64];
    __shared__ __align__(16) unsigned short Bs[128 * 64];

    const unsigned short* arow = xb + (size_t)rblk * 128 * Dz;
    const unsigned short* brow = Wt + (size_t)nblk * 128 * Dz;

    f32x4 acc[4][4];
    #pragma unroll
    for (int mi = 0; mi < 4; ++mi)
        #pragma unroll
        for (int ni = 0; ni < 4; ++ni) acc[mi][ni] = (f32x4){0.f, 0.f, 0.f, 0.f};

    for (int t = 0; t < Dz / 64; ++t) {
        const int k0 = t * 64;
        #pragma unroll
        for (int i = 0; i < 4; ++i) {   // stage A: 128 rows x 64 k
            int ci = tid + i * 256;
            int row = ci >> 3, c = ci & 7;
            uint4 u = *(const uint4*)(arow + (size_t)row * Dz + k0 + c * 8);
            *(uint4*)&As[row * 64 + ((c ^ (row & 7)) << 3)] = u;
        }
        #pragma unroll
        for (int i = 0; i < 4; ++i) {   // stage B: 128 n-rows x 64 k
            int ci = tid + i * 256;
            int row = ci >> 3, c = ci & 7;
            uint4 u = *(const uint4*)(brow + (size_t)row * Dz + k0 + c * 8);
            *(uint4*)&Bs[row * 64 + ((c ^ (row & 7)) << 3)] = u;
        }
        __syncthreads();
        #pragma unroll
        for (int kh = 0; kh < 2; ++kh) {
            bf16x8 a[4], bb[4];
            #pragma unroll
            for (int mi = 0; mi < 4; ++mi)
                a[mi] = *(const bf16x8*)&As[swb(wm * 64 + mi * 16 + l16, kh * 32 + quad * 8)];
            #pragma unroll
            for (int ni = 0; ni < 4; ++ni)
                bb[ni] = *(const bf16x8*)&Bs[swb(wn * 64 + ni * 16 + l16, kh * 32 + quad * 8)];
            #pragma unroll
            for (int mi = 0; mi < 4; ++mi)
                #pragma unroll
                for (int ni = 0; ni < 4; ++ni)
                    acc[mi][ni] = __builtin_amdgcn_mfma_f32_16x16x32_bf16(
                        a[mi], bb[ni], acc[mi][ni], 0, 0, 0);
        }
        __syncthreads();
    }
    // epilogue: n -> (which, h, e); strips never straddle 64/1024 boundaries
    const int row_base = rblk * 128 + wm * 64;
    #pragma unroll
    for (int ni = 0; ni < 4; ++ni) {
        int n_base = nblk * 128 + wn * 64 + ni * 16;
        int which = n_base >> 10, h = (n_base >> 6) & 15, e0 = n_base & 63;
        const float* bp = (which == 0) ? bq : (which == 1) ? bk : bv;
        float bval = bp[h * HDz + e0 + l16];
        unsigned short* base = qkv + (size_t)which * QSZ;
        #pragma unroll
        for (int mi = 0; mi < 4; ++mi)
            #pragma unroll
            for (int r = 0; r < 4; ++r) {
                int row = row_base + mi * 16 + quad * 4 + r;
                int b_ = row >> 11, l = row & 2047;
                base[((size_t)(b_ * Hz + h) * Lz + l) * HDz + e0 + l16] =
                    f2b(acc[mi][ni][r] + bval);
            }
    }
}

// ---------------- Flash attention: S^T + split-K + fixed-shift softmax -----------
__global__ __launch_bounds__(256) void attn_mfma(
    const unsigned short* __restrict__ qkv, const int* __restrict__ mask,
    unsigned short* __restrict__ Opart, float* __restrict__ lsb) {
    const int b = blockIdx.z >> 1, split = blockIdx.z & 1;
    const int h = blockIdx.y, qb = blockIdx.x;
    const int wave = threadIdx.x >> 6, lane = threadIdx.x & 63;
    const int quad = lane >> 4, l16 = lane & 15;
    const unsigned short* Q = qkv + (size_t)((b * Hz + h) * Lz) * HDz;
    const unsigned short* K = Q + QSZ;
    const unsigned short* V = Q + 2 * (size_t)QSZ;

    __shared__ __align__(16) unsigned short Ks[64 * 64];
    __shared__ __align__(16) unsigned short Vt[64 * 64];
    __shared__ __align__(16) unsigned short Pw[4][32 * 64];

    const int row0 = qb * 128 + wave * 32;
    bf16x8 aq[2][2];
    #pragma unroll
    for (int s = 0; s < 2; ++s) {
        const unsigned short* qp = Q + (size_t)(row0 + s * 16 + l16) * HDz;
        aq[s][0] = *(const bf16x8*)(qp + quad * 8);
        aq[s][1] = *(const bf16x8*)(qp + 32 + quad * 8);
    }

    f32x4 O[2][4];
    #pragma unroll
    for (int s = 0; s < 2; ++s)
        #pragma unroll
        for (int nc = 0; nc < 4; ++nc) O[s][nc] = (f32x4){0.f, 0.f, 0.f, 0.f};
    float lacc[2] = {0.f, 0.f};

    const int vp = threadIdx.x & 31, vc = threadIdx.x >> 5;

    for (int t = 0; t < KSPAN / 64; ++t) {
        const int kt0 = split * KSPAN + t * 64;
        #pragma unroll
        for (int i = 0; i < 2; ++i) {
            int ci = threadIdx.x + i * 256;
            int key = ci >> 3, c = ci & 7;
            uint4 u = *(const uint4*)(K + (size_t)(kt0 + key) * HDz + c * 8);
            *(uint4*)&Ks[key * 64 + ((c ^ (key & 7)) << 3)] = u;
        }
        {   // stage V transposed, pair-packed b32 writes
            const unsigned short* vsrc = V + (size_t)(kt0 + 2 * vp) * HDz + vc * 8;
            uint4 u0 = *(const uint4*)vsrc;
            uint4 u1 = *(const uint4*)(vsrc + HDz);
            unsigned short a0[8], a1[8];
            *(uint4*)a0 = u0; *(uint4*)a1 = u1;
            unsigned int* Vt32 = (unsigned int*)Vt;
            #pragma unroll
            for (int j = 0; j < 8; ++j) {
                int row = vc * 8 + j;
                Vt32[row * 32 + ((((vp >> 2) ^ (row & 7)) << 2) + (vp & 3))] =
                    (unsigned int)a0[j] | ((unsigned int)a1[j] << 16);
            }
        }
        unsigned long long bal = __ballot(mask[b * Lz + kt0 + lane] != 0);
        bool allv = (bal == ~0ull);
        __syncthreads();

        float sh[4][4];
        if (allv) {
            #pragma unroll
            for (int kc = 0; kc < 4; ++kc)
                #pragma unroll
                for (int r = 0; r < 4; ++r) sh[kc][r] = -12.0f;
        } else {
            #pragma unroll
            for (int kc = 0; kc < 4; ++kc)
                #pragma unroll
                for (int r = 0; r < 4; ++r)
                    sh[kc][r] = mask[b * Lz + kt0 + kc * 16 + quad * 4 + r] ? -12.0f : -1e9f;
        }

        unsigned short* Pme = Pw[wave];
        #pragma unroll
        for (int kc = 0; kc < 4; ++kc) {
            bf16x8 aK0 = *(const bf16x8*)&Ks[swb(kc * 16 + l16, quad * 8)];
            bf16x8 aK1 = *(const bf16x8*)&Ks[swb(kc * 16 + l16, 32 + quad * 8)];
            #pragma unroll
            for (int s = 0; s < 2; ++s) {
                f32x4 sv = (f32x4){0.f, 0.f, 0.f, 0.f};
                sv = __builtin_amdgcn_mfma_f32_16x16x32_bf16(aK0, aq[s][0], sv, 0, 0, 0);
                sv = __builtin_amdgcn_mfma_f32_16x16x32_bf16(aK1, aq[s][1], sv, 0, 0, 0);
                float p[4];
                #pragma unroll
                for (int r = 0; r < 4; ++r)
                    p[r] = __expf(fmaf(sv[r], 0.125f, sh[kc][r]));
                lacc[s] += (p[0] + p[1]) + (p[2] + p[3]);
                uint2 pk;
                pk.x = pkbf(p[0], p[1]);
                pk.y = pkbf(p[2], p[3]);
                *(uint2*)&Pme[swb(s * 16 + l16, kc * 16 + quad * 4)] = pk;
            }
        }
        #pragma unroll
        for (int kc2 = 0; kc2 < 2; ++kc2) {
            bf16x8 aP0 = *(const bf16x8*)&Pme[swb(l16, kc2 * 32 + quad * 8)];
            bf16x8 aP1 = *(const bf16x8*)&Pme[swb(16 + l16, kc2 * 32 + quad * 8)];
            #pragma unroll
            for (int nc = 0; nc < 4; ++nc) {
                bf16x8 bV = *(const bf16x8*)&Vt[swb(nc * 16 + l16, kc2 * 32 + quad * 8)];
                O[0][nc] = __builtin_amdgcn_mfma_f32_16x16x32_bf16(aP0, bV, O[0][nc], 0, 0, 0);
                O[1][nc] = __builtin_amdgcn_mfma_f32_16x16x32_bf16(aP1, bV, O[1][nc], 0, 0, 0);
            }
        }
        __syncthreads();
    }
    #pragma unroll
    for (int s = 0; s < 2; ++s) {
        lacc[s] += __shfl_xor(lacc[s], 16, 64);
        lacc[s] += __shfl_xor(lacc[s], 32, 64);
    }
    const size_t rowbase = (size_t)(b * Hz + h) * Lz + row0;
    if (quad == 0) {
        atomicAdd(&lsb[rowbase + l16], lacc[0]);
        atomicAdd(&lsb[rowbase + 16 + l16], lacc[1]);
    }
    unsigned short* Os = Opart + (size_t)split * QSZ + rowbase * HDz;
    #pragma unroll
    for (int s = 0; s < 2; ++s)
        #pragma unroll
        for (int r = 0; r < 4; ++r) {
            int row = s * 16 + quad * 4 + r;
            #pragma unroll
            for (int nc = 0; nc < 4; ++nc)
                Os[(size_t)row * HDz + nc * 16 + l16] = f2b(O[s][nc][r]);
        }
}

// ---------------- combine: ctx = (O0 + O1) / lsum -> bf16 into ws Q region -------
__global__ __launch_bounds__(256) void combine(
    const unsigned short* __restrict__ Opart, const float* __restrict__ lsb,
    unsigned short* __restrict__ ctx) {
    int idx8 = (blockIdx.x * 256 + threadIdx.x) * 8;
    float inv = 1.0f / lsb[idx8 >> 6];
    uint4 u0 = *(const uint4*)(Opart + idx8);
    uint4 u1 = *(const uint4*)(Opart + QSZ + idx8);
    unsigned short a0[8], a1[8];
    *(uint4*)a0 = u0; *(uint4*)a1 = u1;
    unsigned int o[4];
    #pragma unroll
    for (int j = 0; j < 4; ++j)
        o[j] = pkbf((b2f(a0[2 * j]) + b2f(a1[2 * j])) * inv,
                    (b2f(a0[2 * j + 1]) + b2f(a1[2 * j + 1])) * inv);
    *(uint4*)(ctx + idx8) = *(uint4*)o;
}

// ---------------- Output projection, MFMA: M=128 N=64 BK=64 (k-chunk = head) -----
__global__ __launch_bounds__(256) void out_mfma(
    const unsigned short* __restrict__ ctx, const unsigned short* __restrict__ Wot,
    const float* __restrict__ bo, float* __restrict__ out) {
    const int r0 = blockIdx.x * 128;
    const int n0 = blockIdx.y * 64;
    const int b = r0 >> 11, lbase = r0 & 2047;
    const int tid = threadIdx.x, wave = tid >> 6, lane = tid & 63;
    const int quad = lane >> 4, l16 = lane & 15;

    __shared__ __align__(16) unsigned short As[128 * 64];
    __shared__ __align__(16) unsigned short Bs[64 * 64];

    f32x4 acc[2][4];
    #pragma unroll
    for (int mi = 0; mi < 2; ++mi)
        #pragma unroll
        for (int ni = 0; ni < 4; ++ni) acc[mi][ni] = (f32x4){0.f, 0.f, 0.f, 0.f};

    for (int t = 0; t < Hz; ++t) {
        const unsigned short* abase = ctx + ((size_t)(b * Hz + t) * Lz + lbase) * HDz;
        #pragma unroll
        for (int i = 0; i < 4; ++i) {
            int ci = tid + i * 256;
            int row = ci >> 3, c = ci & 7;
            uint4 u = *(const uint4*)(abase + (size_t)row * HDz + c * 8);
            *(uint4*)&As[row * 64 + ((c ^ (row & 7)) << 3)] = u;
        }
        #pragma unroll
        for (int i = 0; i < 2; ++i) {
            int ci = tid + i * 256;
            int n = ci >> 3, c = ci & 7;
            uint4 u = *(const uint4*)(Wot + (size_t)(n0 + n) * Dz + t * 64 + c * 8);
            *(uint4*)&Bs[n * 64 + ((c ^ (n & 7)) << 3)] = u;
        }
        __syncthreads();
        #pragma unroll
        for (int kh = 0; kh < 2; ++kh) {
            bf16x8 a[2], bb[4];
            #pragma unroll
            for (int mi = 0; mi < 2; ++mi)
                a[mi] = *(const bf16x8*)&As[swb(wave * 32 + mi * 16 + l16, kh * 32 + quad * 8)];
            #pragma unroll
            for (int ni = 0; ni < 4; ++ni)
                bb[ni] = *(const bf16x8*)&Bs[swb(ni * 16 + l16, kh * 32 + quad * 8)];
            #pragma unroll
            for (int mi = 0; mi < 2; ++mi)
                #pragma unroll
                for (int ni = 0; ni < 4; ++ni)
                    acc[mi][ni] = __builtin_amdgcn_mfma_f32_16x16x32_bf16(
                        a[mi], bb[ni], acc[mi][ni], 0, 0, 0);
        }
        __syncthreads();
    }
    #pragma unroll
    for (int ni = 0; ni < 4; ++ni) {
        float bvv = bo[n0 + ni * 16 + l16];
        #pragma unroll
        for (int mi = 0; mi < 2; ++mi)
            #pragma unroll
            for (int r = 0; r < 4; ++r) {
                int row = r0 + wave * 32 + mi * 16 + quad * 4 + r;
                out[(size_t)row * Dz + n0 + ni * 16 + l16] = acc[mi][ni][r] + bvv;
            }
    }
}

extern "C" void kernel_launch(void* const* d_in, const int* in_sizes, int n_in,
                              void* d_out, int out_size, void* d_ws, size_t ws_size,
                              hipStream_t stream) {
    const float* x    = (const float*)d_in[0];
    const int*   mask = (const int*)d_in[1];
    const float* Wq = (const float*)d_in[2];
    const float* bq = (const float*)d_in[3];
    const float* Wk = (const float*)d_in[4];
    const float* bk = (const float*)d_in[5];
    const float* Wv = (const float*)d_in[6];
    const float* bv = (const float*)d_in[7];
    const float* Wo = (const float*)d_in[8];
    const float* bo = (const float*)d_in[9];
    float* out = (float*)d_out;

    const size_t WT_E  = (size_t)3 * Hz * HDz * Dz;
    const size_t WOT_E = (size_t)Dz * Dz;
    const size_t LS_E  = (size_t)Bz * Hz * Lz;
    const size_t NEED = 256 + ((size_t)3 * QSZ + WT_E + WOT_E) * sizeof(unsigned short)
                        + LS_E * sizeof(float);
    if (ws_size < NEED) {
        ws_sentinel<<<1, 64, 0, stream>>>(out);
        return;
    }
    unsigned short* qkv = (unsigned short*)((char*)d_ws + 256);
    unsigned short* Wt  = qkv + (size_t)3 * QSZ;
    unsigned short* Wot = Wt + WT_E;
    float* lsb = (float*)(Wot + WOT_E);
    unsigned short* xb    = (unsigned short*)d_out;  // dead after qkv_mfma
    unsigned short* Opart = (unsigned short*)d_out;  // live attn -> combine

    prep<<<2048 + 1024 + 64, 256, 0, stream>>>(x, Wq, Wk, Wv, Wo, xb, Wt, Wot, lsb);
    qkv_mfma<<<dim3(32, 24), 256, 0, stream>>>(xb, Wt, bq, bk, bv, qkv);
    attn_mfma<<<dim3(Lz / 128, Hz, Bz * SPLIT), 256, 0, stream>>>(qkv, mask, Opart, lsb);
    combine<<<QSZ / (256 * 8), 256, 0, stream>>>(Opart, lsb, qkv);
    out_mfma<<<dim3((Bz * Lz) / 128, Dz / 64), 256, 0, stream>>>(qkv, Wot, bo, out);
}

// Round 12
// 219.841 us; speedup vs baseline: 1.0988x; 1.0988x over previous
//
#include <hip/hip_runtime.h>

constexpr int Bz = 2, Lz = 2048, Dz = 1024, Hz = 16, HDz = 64;
constexpr int QSZ = Bz * Hz * Lz * HDz;  // 4,194,304 elements per tensor
constexpr int SPLIT = 2;                 // key-range split for attention
constexpr int KSPAN = Lz / SPLIT;        // 1024 keys per split

typedef __attribute__((ext_vector_type(8))) __bf16 bf16x8;
typedef __attribute__((ext_vector_type(2))) __bf16 bf16x2;
typedef __attribute__((ext_vector_type(4))) float f32x4;

__device__ __forceinline__ float b2f(unsigned int u) {
    union { float f; unsigned int i; } c; c.i = u << 16; return c.f;
}
__device__ __forceinline__ unsigned short f2b(float x) {
    union { float f; unsigned int u; } c; c.f = x;
    unsigned int u = c.u;
    return (unsigned short)((u + 0x7fffu + ((u >> 16) & 1u)) >> 16);
}
// HW packed RNE f32->bf16 pair — used ONLY in prep/combine. In attn_mfma it
// regressed 70->88 us (VGPR 64->72, schedule disruption at 4 blocks/CU) [r11].
__device__ __forceinline__ unsigned int pkbf(float a, float b) {
    union { bf16x2 v; unsigned int u; } c;
    c.v = (bf16x2){(__bf16)a, (__bf16)b};
    return c.u;
}
__device__ __forceinline__ void ld8(const float* p, float* f) {
    float4 a = *(const float4*)p, b = *(const float4*)(p + 4);
    f[0] = a.x; f[1] = a.y; f[2] = a.z; f[3] = a.w;
    f[4] = b.x; f[5] = b.y; f[6] = b.z; f[7] = b.w;
}
// ushort index into a [rows][64]-bf16 LDS tile, 16B-chunk XOR swizzle
__device__ __forceinline__ int swb(int row, int e) {
    return row * 64 + ((((e >> 3) ^ row) & 7) << 3) + (e & 7);
}

__global__ void ws_sentinel(float* __restrict__ out) {
    if (threadIdx.x == 0 && blockIdx.x == 0) out[0] = 100.0f;
}

// ---------------- prep: cvt_x + cvt_w + lsb-zero fused (one dispatch) ------------
__global__ __launch_bounds__(256) void prep(
    const float* __restrict__ x,
    const float* __restrict__ Wq, const float* __restrict__ Wk,
    const float* __restrict__ Wv, const float* __restrict__ Wo,
    unsigned short* __restrict__ xb, unsigned short* __restrict__ Wt,
    unsigned short* __restrict__ Wot, float* __restrict__ lsb) {
    const int bid = blockIdx.x, tid = threadIdx.x;
    if (bid < 2048) {                      // cvt_x: 4,194,304 / (256*8) = 2048
        int idx = (bid * 256 + tid) * 8;
        float f[8]; ld8(x + idx, f);
        unsigned int o[4];
        #pragma unroll
        for (int j = 0; j < 4; ++j) o[j] = pkbf(f[2 * j], f[2 * j + 1]);
        *(uint4*)(xb + idx) = *(uint4*)o;
    } else if (bid < 2048 + 1024) {        // cvt_w (transpose to n-major)
        int zz = bid - 2048;
        int z = zz >> 8, y = (zz >> 4) & 15, xk = zz & 15;
        int kseg = xk * 4 + (tid >> 6);
        int k0 = kseg * 16;
        unsigned short o[16];
        if (z < 3) {
            const float* W = (z == 0) ? Wq : (z == 1) ? Wk : Wv;
            const int h = y, n = tid & 63;
            const float* src = W + (size_t)h * Dz * HDz;
            #pragma unroll
            for (int j = 0; j < 16; ++j) o[j] = f2b(src[(size_t)(k0 + j) * HDz + n]);
            unsigned short* dst = Wt + ((size_t)((z * Hz + h) * HDz) + n) * Dz + k0;
            *(uint4*)dst = *(uint4*)o;
            *(uint4*)(dst + 8) = *(uint4*)(o + 8);
        } else {
            const int n = y * 64 + (tid & 63);
            #pragma unroll
            for (int j = 0; j < 16; ++j) o[j] = f2b(Wo[(size_t)(k0 + j) * Dz + n]);
            unsigned short* dst = Wot + (size_t)n * Dz + k0;
            *(uint4*)dst = *(uint4*)o;
            *(uint4*)(dst + 8) = *(uint4*)(o + 8);
        }
    } else {                               // zero lsb (B*H*L = 65536 floats)
        int i = (bid - 3072) * 1024 + tid * 4;
        *(float4*)(lsb + i) = (float4){0.f, 0.f, 0.f, 0.f};
    }
}

// ---------------- QKV projection v2: unified GEMM (4096x1024)x(1024x3072) --------
__global__ __launch_bounds__(256) void qkv_mfma(
    const unsigned short* __restrict__ xb, const unsigned short* __restrict__ Wt,
    const float* __restrict__ bq, const float* __restrict__ bk,
    const float* __restrict__ bv, unsigned short* __restrict__ qkv) {
    const int rblk = blockIdx.x;   // 0..31 (fastest -> B-panel reused within XCD)
    const int nblk = blockIdx.y;   // 0..23
    const int tid = threadIdx.x, wave = tid >> 6, lane = tid & 63;
    const int quad = lane >> 4, l16 = lane & 15;
    const int wm = wave >> 1, wn = wave & 1;

    __shared__ __align__(16) unsigned short As[128 * 64];
    __shared__ __align__(16) unsigned short Bs[128 * 64];

    const unsigned short* arow = xb + (size_t)rblk * 128 * Dz;
    const unsigned short* brow = Wt + (size_t)nblk * 128 * Dz;

    f32x4 acc[4][4];
    #pragma unroll
    for (int mi = 0; mi < 4; ++mi)
        #pragma unroll
        for (int ni = 0; ni < 4; ++ni) acc[mi][ni] = (f32x4){0.f, 0.f, 0.f, 0.f};

    for (int t = 0; t < Dz / 64; ++t) {
        const int k0 = t * 64;
        #pragma unroll
        for (int i = 0; i < 4; ++i) {   // stage A: 128 rows x 64 k
            int ci = tid + i * 256;
            int row = ci >> 3, c = ci & 7;
            uint4 u = *(const uint4*)(arow + (size_t)row * Dz + k0 + c * 8);
            *(uint4*)&As[row * 64 + ((c ^ (row & 7)) << 3)] = u;
        }
        #pragma unroll
        for (int i = 0; i < 4; ++i) {   // stage B: 128 n-rows x 64 k
            int ci = tid + i * 256;
            int row = ci >> 3, c = ci & 7;
            uint4 u = *(const uint4*)(brow + (size_t)row * Dz + k0 + c * 8);
            *(uint4*)&Bs[row * 64 + ((c ^ (row & 7)) << 3)] = u;
        }
        __syncthreads();
        #pragma unroll
        for (int kh = 0; kh < 2; ++kh) {
            bf16x8 a[4], bb[4];
            #pragma unroll
            for (int mi = 0; mi < 4; ++mi)
                a[mi] = *(const bf16x8*)&As[swb(wm * 64 + mi * 16 + l16, kh * 32 + quad * 8)];
            #pragma unroll
            for (int ni = 0; ni < 4; ++ni)
                bb[ni] = *(const bf16x8*)&Bs[swb(wn * 64 + ni * 16 + l16, kh * 32 + quad * 8)];
            #pragma unroll
            for (int mi = 0; mi < 4; ++mi)
                #pragma unroll
                for (int ni = 0; ni < 4; ++ni)
                    acc[mi][ni] = __builtin_amdgcn_mfma_f32_16x16x32_bf16(
                        a[mi], bb[ni], acc[mi][ni], 0, 0, 0);
        }
        __syncthreads();
    }
    const int row_base = rblk * 128 + wm * 64;
    #pragma unroll
    for (int ni = 0; ni < 4; ++ni) {
        int n_base = nblk * 128 + wn * 64 + ni * 16;
        int which = n_base >> 10, h = (n_base >> 6) & 15, e0 = n_base & 63;
        const float* bp = (which == 0) ? bq : (which == 1) ? bk : bv;
        float bval = bp[h * HDz + e0 + l16];
        unsigned short* base = qkv + (size_t)which * QSZ;
        #pragma unroll
        for (int mi = 0; mi < 4; ++mi)
            #pragma unroll
            for (int r = 0; r < 4; ++r) {
                int row = row_base + mi * 16 + quad * 4 + r;
                int b_ = row >> 11, l = row & 2047;
                base[((size_t)(b_ * Hz + h) * Lz + l) * HDz + e0 + l16] =
                    f2b(acc[mi][ni][r] + bval);
            }
    }
}

// ---------------- Flash attention: S^T + split-K + XCD-swizzled grid -------------
// 1-D grid of 1024. combo=(h,b,split) varies fastest (spread over XCDs); qb
// advances in strides of 64 (== 0 mod 8) so all 16 qb-blocks of one combo land
// on ONE XCD -> per-XCD K/V working set 2.1 MB < 4 MB L2 (was 16 MB).
__global__ __launch_bounds__(256) void attn_mfma(
    const unsigned short* __restrict__ qkv, const int* __restrict__ mask,
    unsigned short* __restrict__ Opart, float* __restrict__ lsb) {
    const int bid = blockIdx.x;
    const int combo = bid & 63, qb = bid >> 6;
    const int h = combo & 15, z = combo >> 4;
    const int b = z >> 1, split = z & 1;
    const int wave = threadIdx.x >> 6, lane = threadIdx.x & 63;
    const int quad = lane >> 4, l16 = lane & 15;
    const unsigned short* Q = qkv + (size_t)((b * Hz + h) * Lz) * HDz;
    const unsigned short* K = Q + QSZ;
    const unsigned short* V = Q + 2 * (size_t)QSZ;

    __shared__ __align__(16) unsigned short Ks[64 * 64];
    __shared__ __align__(16) unsigned short Vt[64 * 64];
    __shared__ __align__(16) unsigned short Pw[4][32 * 64];

    const int row0 = qb * 128 + wave * 32;
    bf16x8 aq[2][2];
    #pragma unroll
    for (int s = 0; s < 2; ++s) {
        const unsigned short* qp = Q + (size_t)(row0 + s * 16 + l16) * HDz;
        aq[s][0] = *(const bf16x8*)(qp + quad * 8);
        aq[s][1] = *(const bf16x8*)(qp + 32 + quad * 8);
    }

    f32x4 O[2][4];
    #pragma unroll
    for (int s = 0; s < 2; ++s)
        #pragma unroll
        for (int nc = 0; nc < 4; ++nc) O[s][nc] = (f32x4){0.f, 0.f, 0.f, 0.f};
    float lacc[2] = {0.f, 0.f};

    const int vp = threadIdx.x & 31, vc = threadIdx.x >> 5;

    for (int t = 0; t < KSPAN / 64; ++t) {
        const int kt0 = split * KSPAN + t * 64;
        #pragma unroll
        for (int i = 0; i < 2; ++i) {
            int ci = threadIdx.x + i * 256;
            int key = ci >> 3, c = ci & 7;
            uint4 u = *(const uint4*)(K + (size_t)(kt0 + key) * HDz + c * 8);
            *(uint4*)&Ks[key * 64 + ((c ^ (key & 7)) << 3)] = u;
        }
        {   // stage V transposed, pair-packed b32 writes
            const unsigned short* vsrc = V + (size_t)(kt0 + 2 * vp) * HDz + vc * 8;
            uint4 u0 = *(const uint4*)vsrc;
            uint4 u1 = *(const uint4*)(vsrc + HDz);
            unsigned short a0[8], a1[8];
            *(uint4*)a0 = u0; *(uint4*)a1 = u1;
            unsigned int* Vt32 = (unsigned int*)Vt;
            #pragma unroll
            for (int j = 0; j < 8; ++j) {
                int row = vc * 8 + j;
                Vt32[row * 32 + ((((vp >> 2) ^ (row & 7)) << 2) + (vp & 3))] =
                    (unsigned int)a0[j] | ((unsigned int)a1[j] << 16);
            }
        }
        unsigned long long bal = __ballot(mask[b * Lz + kt0 + lane] != 0);
        bool allv = (bal == ~0ull);
        __syncthreads();

        float sh[4][4];
        if (allv) {
            #pragma unroll
            for (int kc = 0; kc < 4; ++kc)
                #pragma unroll
                for (int r = 0; r < 4; ++r) sh[kc][r] = -12.0f;
        } else {
            #pragma unroll
            for (int kc = 0; kc < 4; ++kc)
                #pragma unroll
                for (int r = 0; r < 4; ++r)
                    sh[kc][r] = mask[b * Lz + kt0 + kc * 16 + quad * 4 + r] ? -12.0f : -1e9f;
        }

        unsigned short* Pme = Pw[wave];
        #pragma unroll
        for (int kc = 0; kc < 4; ++kc) {
            bf16x8 aK0 = *(const bf16x8*)&Ks[swb(kc * 16 + l16, quad * 8)];
            bf16x8 aK1 = *(const bf16x8*)&Ks[swb(kc * 16 + l16, 32 + quad * 8)];
            #pragma unroll
            for (int s = 0; s < 2; ++s) {
                f32x4 sv = (f32x4){0.f, 0.f, 0.f, 0.f};
                sv = __builtin_amdgcn_mfma_f32_16x16x32_bf16(aK0, aq[s][0], sv, 0, 0, 0);
                sv = __builtin_amdgcn_mfma_f32_16x16x32_bf16(aK1, aq[s][1], sv, 0, 0, 0);
                float p[4];
                #pragma unroll
                for (int r = 0; r < 4; ++r)
                    p[r] = __expf(fmaf(sv[r], 0.125f, sh[kc][r]));
                lacc[s] += (p[0] + p[1]) + (p[2] + p[3]);
                uint2 pk;   // manual RNE pack (f2b): r11 showed HW-cast regresses here
                pk.x = (unsigned int)f2b(p[0]) | ((unsigned int)f2b(p[1]) << 16);
                pk.y = (unsigned int)f2b(p[2]) | ((unsigned int)f2b(p[3]) << 16);
                *(uint2*)&Pme[swb(s * 16 + l16, kc * 16 + quad * 4)] = pk;
            }
        }
        #pragma unroll
        for (int kc2 = 0; kc2 < 2; ++kc2) {
            bf16x8 aP0 = *(const bf16x8*)&Pme[swb(l16, kc2 * 32 + quad * 8)];
            bf16x8 aP1 = *(const bf16x8*)&Pme[swb(16 + l16, kc2 * 32 + quad * 8)];
            #pragma unroll
            for (int nc = 0; nc < 4; ++nc) {
                bf16x8 bV = *(const bf16x8*)&Vt[swb(nc * 16 + l16, kc2 * 32 + quad * 8)];
                O[0][nc] = __builtin_amdgcn_mfma_f32_16x16x32_bf16(aP0, bV, O[0][nc], 0, 0, 0);
                O[1][nc] = __builtin_amdgcn_mfma_f32_16x16x32_bf16(aP1, bV, O[1][nc], 0, 0, 0);
            }
        }
        __syncthreads();
    }
    #pragma unroll
    for (int s = 0; s < 2; ++s) {
        lacc[s] += __shfl_xor(lacc[s], 16, 64);
        lacc[s] += __shfl_xor(lacc[s], 32, 64);
    }
    const size_t rowbase = (size_t)(b * Hz + h) * Lz + row0;
    if (quad == 0) {
        atomicAdd(&lsb[rowbase + l16], lacc[0]);
        atomicAdd(&lsb[rowbase + 16 + l16], lacc[1]);
    }
    unsigned short* Os = Opart + (size_t)split * QSZ + rowbase * HDz;
    #pragma unroll
    for (int s = 0; s < 2; ++s)
        #pragma unroll
        for (int r = 0; r < 4; ++r) {
            int row = s * 16 + quad * 4 + r;
            #pragma unroll
            for (int nc = 0; nc < 4; ++nc)
                Os[(size_t)row * HDz + nc * 16 + l16] = f2b(O[s][nc][r]);
        }
}

// ---------------- combine: ctx = (O0 + O1) / lsum -> bf16 into ws Q region -------
__global__ __launch_bounds__(256) void combine(
    const unsigned short* __restrict__ Opart, const float* __restrict__ lsb,
    unsigned short* __restrict__ ctx) {
    int idx8 = (blockIdx.x * 256 + threadIdx.x) * 8;
    float inv = 1.0f / lsb[idx8 >> 6];
    uint4 u0 = *(const uint4*)(Opart + idx8);
    uint4 u1 = *(const uint4*)(Opart + QSZ + idx8);
    unsigned short a0[8], a1[8];
    *(uint4*)a0 = u0; *(uint4*)a1 = u1;
    unsigned int o[4];
    #pragma unroll
    for (int j = 0; j < 4; ++j)
        o[j] = pkbf((b2f(a0[2 * j]) + b2f(a1[2 * j])) * inv,
                    (b2f(a0[2 * j + 1]) + b2f(a1[2 * j + 1])) * inv);
    *(uint4*)(ctx + idx8) = *(uint4*)o;
}

// ---------------- Output projection, MFMA: M=128 N=64 BK=64 (k-chunk = head) -----
__global__ __launch_bounds__(256) void out_mfma(
    const unsigned short* __restrict__ ctx, const unsigned short* __restrict__ Wot,
    const float* __restrict__ bo, float* __restrict__ out) {
    const int r0 = blockIdx.x * 128;
    const int n0 = blockIdx.y * 64;
    const int b = r0 >> 11, lbase = r0 & 2047;
    const int tid = threadIdx.x, wave = tid >> 6, lane = tid & 63;
    const int quad = lane >> 4, l16 = lane & 15;

    __shared__ __align__(16) unsigned short As[128 * 64];
    __shared__ __align__(16) unsigned short Bs[64 * 64];

    f32x4 acc[2][4];
    #pragma unroll
    for (int mi = 0; mi < 2; ++mi)
        #pragma unroll
        for (int ni = 0; ni < 4; ++ni) acc[mi][ni] = (f32x4){0.f, 0.f, 0.f, 0.f};

    for (int t = 0; t < Hz; ++t) {
        const unsigned short* abase = ctx + ((size_t)(b * Hz + t) * Lz + lbase) * HDz;
        #pragma unroll
        for (int i = 0; i < 4; ++i) {
            int ci = tid + i * 256;
            int row = ci >> 3, c = ci & 7;
            uint4 u = *(const uint4*)(abase + (size_t)row * HDz + c * 8);
            *(uint4*)&As[row * 64 + ((c ^ (row & 7)) << 3)] = u;
        }
        #pragma unroll
        for (int i = 0; i < 2; ++i) {
            int ci = tid + i * 256;
            int n = ci >> 3, c = ci & 7;
            uint4 u = *(const uint4*)(Wot + (size_t)(n0 + n) * Dz + t * 64 + c * 8);
            *(uint4*)&Bs[n * 64 + ((c ^ (n & 7)) << 3)] = u;
        }
        __syncthreads();
        #pragma unroll
        for (int kh = 0; kh < 2; ++kh) {
            bf16x8 a[2], bb[4];
            #pragma unroll
            for (int mi = 0; mi < 2; ++mi)
                a[mi] = *(const bf16x8*)&As[swb(wave * 32 + mi * 16 + l16, kh * 32 + quad * 8)];
            #pragma unroll
            for (int ni = 0; ni < 4; ++ni)
                bb[ni] = *(const bf16x8*)&Bs[swb(ni * 16 + l16, kh * 32 + quad * 8)];
            #pragma unroll
            for (int mi = 0; mi < 2; ++mi)
                #pragma unroll
                for (int ni = 0; ni < 4; ++ni)
                    acc[mi][ni] = __builtin_amdgcn_mfma_f32_16x16x32_bf16(
                        a[mi], bb[ni], acc[mi][ni], 0, 0, 0);
        }
        __syncthreads();
    }
    #pragma unroll
    for (int ni = 0; ni < 4; ++ni) {
        float bvv = bo[n0 + ni * 16 + l16];
        #pragma unroll
        for (int mi = 0; mi < 2; ++mi)
            #pragma unroll
            for (int r = 0; r < 4; ++r) {
                int row = r0 + wave * 32 + mi * 16 + quad * 4 + r;
                out[(size_t)row * Dz + n0 + ni * 16 + l16] = acc[mi][ni][r] + bvv;
            }
    }
}

extern "C" void kernel_launch(void* const* d_in, const int* in_sizes, int n_in,
                              void* d_out, int out_size, void* d_ws, size_t ws_size,
                              hipStream_t stream) {
    const float* x    = (const float*)d_in[0];
    const int*   mask = (const int*)d_in[1];
    const float* Wq = (const float*)d_in[2];
    const float* bq = (const float*)d_in[3];
    const float* Wk = (const float*)d_in[4];
    const float* bk = (const float*)d_in[5];
    const float* Wv = (const float*)d_in[6];
    const float* bv = (const float*)d_in[7];
    const float* Wo = (const float*)d_in[8];
    const float* bo = (const float*)d_in[9];
    float* out = (float*)d_out;

    const size_t WT_E  = (size_t)3 * Hz * HDz * Dz;
    const size_t WOT_E = (size_t)Dz * Dz;
    const size_t LS_E  = (size_t)Bz * Hz * Lz;
    const size_t NEED = 256 + ((size_t)3 * QSZ + WT_E + WOT_E) * sizeof(unsigned short)
                        + LS_E * sizeof(float);
    if (ws_size < NEED) {
        ws_sentinel<<<1, 64, 0, stream>>>(out);
        return;
    }
    unsigned short* qkv = (unsigned short*)((char*)d_ws + 256);
    unsigned short* Wt  = qkv + (size_t)3 * QSZ;
    unsigned short* Wot = Wt + WT_E;
    float* lsb = (float*)(Wot + WOT_E);
    unsigned short* xb    = (unsigned short*)d_out;  // dead after qkv_mfma
    unsigned short* Opart = (unsigned short*)d_out;  // live attn -> combine

    prep<<<2048 + 1024 + 64, 256, 0, stream>>>(x, Wq, Wk, Wv, Wo, xb, Wt, Wot, lsb);
    qkv_mfma<<<dim3(32, 24), 256, 0, stream>>>(xb, Wt, bq, bk, bv, qkv);
    attn_mfma<<<1024, 256, 0, stream>>>(qkv, mask, Opart, lsb);
    combine<<<QSZ / (256 * 8), 256, 0, stream>>>(Opart, lsb, qkv);
    out_mfma<<<dim3((Bz * Lz) / 128, Dz / 64), 256, 0, stream>>>(qkv, Wot, bo, out);
}